// Round 3
// baseline (375.669 us; speedup 1.0000x reference)
//
#include <hip/hip_runtime.h>

#ifndef __has_builtin
#define __has_builtin(x) 0
#endif

__device__ __forceinline__ float fast_exp2(float x) {
#if __has_builtin(__builtin_amdgcn_exp2f)
    return __builtin_amdgcn_exp2f(x);
#else
    return exp2f(x);
#endif
}

// Canonical CDNA wave64 sum via DPP (VALU pipe, not DS):
// row_shr 1/2/4/8 (bound_ctrl: invalid->0), then row_bcast15 (rows 1,3),
// row_bcast31 (rows 2,3). Lane 63 ends with the full 64-lane sum.
__device__ __forceinline__ float wave_sum_dpp(float x) {
    int v;
    v = __builtin_amdgcn_update_dpp(0, __float_as_int(x), 0x111, 0xf, 0xf, true);
    x += __int_as_float(v);
    v = __builtin_amdgcn_update_dpp(0, __float_as_int(x), 0x112, 0xf, 0xf, true);
    x += __int_as_float(v);
    v = __builtin_amdgcn_update_dpp(0, __float_as_int(x), 0x114, 0xf, 0xf, true);
    x += __int_as_float(v);
    v = __builtin_amdgcn_update_dpp(0, __float_as_int(x), 0x118, 0xf, 0xf, true);
    x += __int_as_float(v);
    v = __builtin_amdgcn_update_dpp(0, __float_as_int(x), 0x142, 0xa, 0xf, false);
    x += __int_as_float(v);
    v = __builtin_amdgcn_update_dpp(0, __float_as_int(x), 0x143, 0xc, 0xf, false);
    x += __int_as_float(v);
    return x;
}

// Block-wide barrier WITHOUT the vmcnt(0) drain that __syncthreads emits.
// Only LDS ops (ds_write of sP/sInvD) need visibility across the barrier;
// in-flight global prefetch loads (read-only, into private VGPRs) may
// legally stay outstanding. This is the key to overlapping part k+1's HBM
// reads with part k's compute.
__device__ __forceinline__ void sync_lds() {
    asm volatile("s_waitcnt lgkmcnt(0)" ::: "memory");
    __builtin_amdgcn_s_barrier();
    asm volatile("" ::: "memory");
}

constexpr int   kB      = 256;
constexpr int   kC      = 1024;
constexpr int   kG      = 13;
constexpr int   kP      = kG * kG;                // 169
constexpr int   kBufP   = 22;                     // max positions per part
constexpr float kEps    = 1e-6f;
constexpr float kZ      = 17.079468445347132f;    // 2*pi*e
constexpr float kLog2e  = 1.4426950408889634f;
constexpr float kInv169 = 1.0f / 169.0f;
constexpr float kScale  = 1.0f / (256.0f * 1024.0f);

// One pipelined part step. START/PP compile-time; NPP = next part's size
// (0 for the last part). cur holds raw x values for [START, START+PP);
// nxt receives the prefetch for the next part. Accumulation order over
// global positions is ascending and identical to the verified R2 kernel
// (zero-adds removed, which is bitwise neutral) -> absmax stays 0.
template<int START, int PP, int NPP>
__device__ __forceinline__ void do_part(
    const float* __restrict__ xb, int tid, int lane, int wid,
    float (&cur)[kBufP], float (&nxt)[kBufP],
    float& S0, float& S1x, float& S1y, float& S2x, float& S2y,
    float* __restrict__ sP, float* __restrict__ sInvD)
{
    // 1) prefetch next part into nxt (issues early; completion awaited
    //    only at next part's exp ladder)
    if (NPP > 0) {
        const float* __restrict__ xn = xb + (size_t)(START + PP) * kC + tid;
        #pragma unroll
        for (int i = 0; i < NPP; ++i)
            nxt[i] = xn[(size_t)i * kC];
    }

    // 2) exp (waits only on cur's loads, issued one part earlier)
    #pragma unroll
    for (int i = 0; i < PP; ++i)
        cur[i] = fast_exp2(cur[i] * kLog2e);

    // 3) per-position wave partial sums on the VALU pipe
    #pragma unroll
    for (int i = 0; i < PP; ++i) {
        const float s = wave_sum_dpp(cur[i]);
        if (lane == 63) sP[i * 16 + wid] = s;
    }
    sync_lds();

    // 4) 16-way cross-wave tree -> per-position inverse denominator
    if (tid < PP) {
        float d = 0.f;
        #pragma unroll
        for (int w = 0; w < 16; ++w)
            d += sP[tid * 16 + w];
        sInvD[tid] = 1.0f / (d + 1e-30f);
    }
    sync_lds();

    // 5) stats accumulation, positions in ascending global order
    int h = START / kG;
    int w = START - (START / kG) * kG;
    #pragma unroll
    for (int i = 0; i < PP; ++i) {
        const float f  = cur[i] * sInvD[i];
        const float fx = (float)(h + 1);
        const float fy = (float)(w + 1);
        S0  += f;
        S1x  = fmaf(fx,      f, S1x);
        S1y  = fmaf(fy,      f, S1y);
        S2x  = fmaf(fx * fx, f, S2x);
        S2y  = fmaf(fy * fy, f, S2y);
        ++w;
        if (w == kG) { w = 0; ++h; }  // folds to cndmask after unroll
    }
    // sP/sInvD reuse across parts is race-free: writes for part k+1 happen
    // only after every wave passed barrier2 of part k (so the tree reader
    // and all sInvD consumers of part k are done).
}

// ---------------------------------------------------------------------------
// Fully fused, software-pipelined kernel: one block per batch b, 1024
// threads (thread = channel). 8 parts of 21/21/21/21/21/21/21/22 positions,
// double-buffered e-regs (22+22), raw lgkm-only barriers so prefetch
// global loads stay in flight across barriers. Input bytes touched exactly
// once (177 MB -> HBM floor ~28 us).
// ---------------------------------------------------------------------------
__global__ __launch_bounds__(1024, 4)
void fused_kernel(const float* __restrict__ x, float* __restrict__ out)
{
    __shared__ float sP[kBufP * 16];      // per-(position, wave) partials
    __shared__ float sInvD[kBufP];
    __shared__ float sred[16];

    const int tid  = threadIdx.x;
    const int lane = tid & 63;
    const int wid  = tid >> 6;
    const int b    = blockIdx.x;

    const float* __restrict__ xb = x + (size_t)b * kP * kC;

    float e0[kBufP], e1[kBufP];
    float S0 = 0.f, S1x = 0.f, S1y = 0.f, S2x = 0.f, S2y = 0.f;

    // prologue: load part 0
    {
        const float* __restrict__ xc = xb + tid;
        #pragma unroll
        for (int i = 0; i < 21; ++i)
            e0[i] = xc[(size_t)i * kC];
    }

    do_part<  0, 21, 21>(xb, tid, lane, wid, e0, e1, S0, S1x, S1y, S2x, S2y, sP, sInvD);
    do_part< 21, 21, 21>(xb, tid, lane, wid, e1, e0, S0, S1x, S1y, S2x, S2y, sP, sInvD);
    do_part< 42, 21, 21>(xb, tid, lane, wid, e0, e1, S0, S1x, S1y, S2x, S2y, sP, sInvD);
    do_part< 63, 21, 21>(xb, tid, lane, wid, e1, e0, S0, S1x, S1y, S2x, S2y, sP, sInvD);
    do_part< 84, 21, 21>(xb, tid, lane, wid, e0, e1, S0, S1x, S1y, S2x, S2y, sP, sInvD);
    do_part<105, 21, 21>(xb, tid, lane, wid, e1, e0, S0, S1x, S1y, S2x, S2y, sP, sInvD);
    do_part<126, 21, 22>(xb, tid, lane, wid, e0, e1, S0, S1x, S1y, S2x, S2y, sP, sInvD);
    do_part<147, 22,  0>(xb, tid, lane, wid, e1, e0, S0, S1x, S1y, S2x, S2y, sP, sInvD);

    // det epilogue per (b, c) and block-wide mean contribution
    const float s   = S0 + kEps;
    const float is  = 1.0f / s;
    const float mx  = S1x * is;
    const float my  = S1y * is;
    const float nx  = S2x - mx * (2.0f * S1x - mx * S0);
    const float ny  = S2y - my * (2.0f * S1y - my * S0);
    const float t   = (nx + ny) * is * kInv169;
    float det = t * t * kZ;

    #pragma unroll
    for (int m = 1; m < 64; m <<= 1)
        det += __shfl_xor(det, m);

    if (lane == 0) sred[wid] = det;
    __syncthreads();
    if (wid == 0) {
        float v = (lane < 16) ? sred[lane] : 0.0f;
        #pragma unroll
        for (int m = 1; m < 16; m <<= 1)
            v += __shfl_xor(v, m);
        if (lane == 0) atomicAdd(out, v * kScale);
    }
}

extern "C" void kernel_launch(void* const* d_in, const int* in_sizes, int n_in,
                              void* d_out, int out_size, void* d_ws, size_t ws_size,
                              hipStream_t stream)
{
    const float* x   = (const float*)d_in[0];
    float*       out = (float*)d_out;

    // out is tiny (scalar compare); measured ~free in R0.
    hipMemsetAsync(out, 0, sizeof(float) * (size_t)out_size, stream);
    fused_kernel<<<dim3(kB), dim3(1024), 0, stream>>>(x, out);
}

// Round 4
// 371.438 us; speedup vs baseline: 1.0114x; 1.0114x over previous
//
#include <hip/hip_runtime.h>

#ifndef __has_builtin
#define __has_builtin(x) 0
#endif

__device__ __forceinline__ float fast_exp2(float x) {
#if __has_builtin(__builtin_amdgcn_exp2f)
    return __builtin_amdgcn_exp2f(x);
#else
    return exp2f(x);
#endif
}

// Canonical CDNA wave64 sum via DPP (VALU pipe, not DS):
// row_shr 1/2/4/8 (bound_ctrl: invalid->0), then row_bcast15 (rows 1,3),
// row_bcast31 (rows 2,3). Lane 63 ends with the full 64-lane sum.
__device__ __forceinline__ float wave_sum_dpp(float x) {
    int v;
    v = __builtin_amdgcn_update_dpp(0, __float_as_int(x), 0x111, 0xf, 0xf, true);
    x += __int_as_float(v);
    v = __builtin_amdgcn_update_dpp(0, __float_as_int(x), 0x112, 0xf, 0xf, true);
    x += __int_as_float(v);
    v = __builtin_amdgcn_update_dpp(0, __float_as_int(x), 0x114, 0xf, 0xf, true);
    x += __int_as_float(v);
    v = __builtin_amdgcn_update_dpp(0, __float_as_int(x), 0x118, 0xf, 0xf, true);
    x += __int_as_float(v);
    v = __builtin_amdgcn_update_dpp(0, __float_as_int(x), 0x142, 0xa, 0xf, false);
    x += __int_as_float(v);
    v = __builtin_amdgcn_update_dpp(0, __float_as_int(x), 0x143, 0xc, 0xf, false);
    x += __int_as_float(v);
    return x;
}

// Block-wide barrier WITHOUT the vmcnt(0) drain that __syncthreads emits.
// Only LDS ops (sP/sInvD) need visibility across the barrier; in-flight
// global prefetch loads (read-only, into private VGPRs) legally stay
// outstanding, overlapping part k+1's HBM reads with part k's compute.
__device__ __forceinline__ void sync_lds() {
    asm volatile("s_waitcnt lgkmcnt(0)" ::: "memory");
    __builtin_amdgcn_s_barrier();
    asm volatile("" ::: "memory");
}

constexpr int   kB      = 256;
constexpr int   kC      = 1024;
constexpr int   kG      = 13;
constexpr int   kP      = kG * kG;                // 169
constexpr int   kRP     = 13;                     // positions per part = one row
constexpr float kEps    = 1e-6f;
constexpr float kZ      = 17.079468445347132f;    // 2*pi*e
constexpr float kLog2e  = 1.4426950408889634f;
constexpr float kInv169 = 1.0f / 169.0f;
constexpr float kScale  = 1.0f / (256.0f * 1024.0f);

// One pipelined row step. PART (= grid row h) is compile-time; LAST part
// skips the prefetch. cur holds raw x for row PART; nxt receives the
// prefetch of row PART+1. Position accumulation order is ascending and
// op-for-op identical to the verified R2/R3 kernels -> absmax stays 0.
// Register budget is the whole design: e0[13]+e1[13]+overhead ~= 50 VGPR,
// spill-free even at the allocator's preferred 64-VGPR (2 blocks/CU) budget.
template<int PART, bool LAST>
__device__ __forceinline__ void do_row(
    const float* __restrict__ xb, int tid, int lane, int wid,
    float (&cur)[kRP], float (&nxt)[kRP],
    float& S0, float& S1x, float& S1y, float& S2x, float& S2y,
    float* __restrict__ sP, float* __restrict__ sInvD)
{
    constexpr int START = PART * kRP;

    // 1) prefetch next row (completion awaited only at next part's exp)
    if (!LAST) {
        const float* __restrict__ xn = xb + (size_t)(START + kRP) * kC + tid;
        #pragma unroll
        for (int i = 0; i < kRP; ++i)
            nxt[i] = xn[(size_t)i * kC];
    }

    // 2) exp (waits only on cur's loads, issued one part earlier)
    #pragma unroll
    for (int i = 0; i < kRP; ++i)
        cur[i] = fast_exp2(cur[i] * kLog2e);

    // 3) per-position wave partial sums on the VALU pipe
    #pragma unroll
    for (int i = 0; i < kRP; ++i) {
        const float s = wave_sum_dpp(cur[i]);
        if (lane == 63) sP[i * 16 + wid] = s;
    }
    sync_lds();

    // 4) 16-way cross-wave tree -> per-position inverse denominator
    if (tid < kRP) {
        float d = 0.f;
        #pragma unroll
        for (int w = 0; w < 16; ++w)
            d += sP[tid * 16 + w];
        sInvD[tid] = 1.0f / (d + 1e-30f);
    }
    sync_lds();

    // 5) stats: h = PART constant, w = i. Same fmaf sequence/values as the
    //    verified kernels (fx=(float)(h+1), fy=(float)(w+1)).
    const float fx = (float)(PART + 1);
    #pragma unroll
    for (int i = 0; i < kRP; ++i) {
        const float f  = cur[i] * sInvD[i];
        const float fy = (float)(i + 1);
        S0  += f;
        S1x  = fmaf(fx,      f, S1x);
        S1y  = fmaf(fy,      f, S1y);
        S2x  = fmaf(fx * fx, f, S2x);
        S2y  = fmaf(fy * fy, f, S2y);
    }
    // sP/sInvD reuse across parts is race-free: writes for part k+1 happen
    // only after every wave passed barrier2 of part k (so the tree reader
    // and all sInvD consumers of part k are done).
}

// ---------------------------------------------------------------------------
// Fully fused, software-pipelined kernel: one block per batch b, 1024
// threads (thread = channel). 13 parts of 13 positions (one grid row each),
// double-buffered e-regs (13+13), raw lgkm-only barriers so prefetch global
// loads stay in flight across barriers. Input bytes touched exactly once
// (177 MB -> HBM floor ~28 us). Designed to fit the 64-VGPR / 2-blocks-per-CU
// budget with ZERO scratch (R3's 240 MB of spill traffic was the regression).
// ---------------------------------------------------------------------------
__global__ __launch_bounds__(1024, 4)
void fused_kernel(const float* __restrict__ x, float* __restrict__ out)
{
    __shared__ float sP[kRP * 16];        // per-(position, wave) partials
    __shared__ float sInvD[kRP];
    __shared__ float sred[16];

    const int tid  = threadIdx.x;
    const int lane = tid & 63;
    const int wid  = tid >> 6;
    const int b    = blockIdx.x;

    const float* __restrict__ xb = x + (size_t)b * kP * kC;

    float e0[kRP], e1[kRP];
    float S0 = 0.f, S1x = 0.f, S1y = 0.f, S2x = 0.f, S2y = 0.f;

    // prologue: load row 0
    {
        const float* __restrict__ xc = xb + tid;
        #pragma unroll
        for (int i = 0; i < kRP; ++i)
            e0[i] = xc[(size_t)i * kC];
    }

    do_row< 0, false>(xb, tid, lane, wid, e0, e1, S0, S1x, S1y, S2x, S2y, sP, sInvD);
    do_row< 1, false>(xb, tid, lane, wid, e1, e0, S0, S1x, S1y, S2x, S2y, sP, sInvD);
    do_row< 2, false>(xb, tid, lane, wid, e0, e1, S0, S1x, S1y, S2x, S2y, sP, sInvD);
    do_row< 3, false>(xb, tid, lane, wid, e1, e0, S0, S1x, S1y, S2x, S2y, sP, sInvD);
    do_row< 4, false>(xb, tid, lane, wid, e0, e1, S0, S1x, S1y, S2x, S2y, sP, sInvD);
    do_row< 5, false>(xb, tid, lane, wid, e1, e0, S0, S1x, S1y, S2x, S2y, sP, sInvD);
    do_row< 6, false>(xb, tid, lane, wid, e0, e1, S0, S1x, S1y, S2x, S2y, sP, sInvD);
    do_row< 7, false>(xb, tid, lane, wid, e1, e0, S0, S1x, S1y, S2x, S2y, sP, sInvD);
    do_row< 8, false>(xb, tid, lane, wid, e0, e1, S0, S1x, S1y, S2x, S2y, sP, sInvD);
    do_row< 9, false>(xb, tid, lane, wid, e1, e0, S0, S1x, S1y, S2x, S2y, sP, sInvD);
    do_row<10, false>(xb, tid, lane, wid, e0, e1, S0, S1x, S1y, S2x, S2y, sP, sInvD);
    do_row<11, false>(xb, tid, lane, wid, e1, e0, S0, S1x, S1y, S2x, S2y, sP, sInvD);
    do_row<12, true >(xb, tid, lane, wid, e0, e1, S0, S1x, S1y, S2x, S2y, sP, sInvD);

    // det epilogue per (b, c) and block-wide mean contribution
    const float s   = S0 + kEps;
    const float is  = 1.0f / s;
    const float mx  = S1x * is;
    const float my  = S1y * is;
    const float nx  = S2x - mx * (2.0f * S1x - mx * S0);
    const float ny  = S2y - my * (2.0f * S1y - my * S0);
    const float t   = (nx + ny) * is * kInv169;
    float det = t * t * kZ;

    #pragma unroll
    for (int m = 1; m < 64; m <<= 1)
        det += __shfl_xor(det, m);

    if (lane == 0) sred[wid] = det;
    __syncthreads();
    if (wid == 0) {
        float v = (lane < 16) ? sred[lane] : 0.0f;
        #pragma unroll
        for (int m = 1; m < 16; m <<= 1)
            v += __shfl_xor(v, m);
        if (lane == 0) atomicAdd(out, v * kScale);
    }
}

extern "C" void kernel_launch(void* const* d_in, const int* in_sizes, int n_in,
                              void* d_out, int out_size, void* d_ws, size_t ws_size,
                              hipStream_t stream)
{
    const float* x   = (const float*)d_in[0];
    float*       out = (float*)d_out;

    // out is tiny (scalar compare); measured ~free in R0.
    hipMemsetAsync(out, 0, sizeof(float) * (size_t)out_size, stream);
    fused_kernel<<<dim3(kB), dim3(1024), 0, stream>>>(x, out);
}

// Round 5
// 368.945 us; speedup vs baseline: 1.0182x; 1.0068x over previous
//
#include <hip/hip_runtime.h>

#ifndef __has_builtin
#define __has_builtin(x) 0
#endif

__device__ __forceinline__ float fast_exp2(float x) {
#if __has_builtin(__builtin_amdgcn_exp2f)
    return __builtin_amdgcn_exp2f(x);
#else
    return exp2f(x);
#endif
}

// Canonical CDNA wave64 sum via DPP (VALU pipe, not DS):
// row_shr 1/2/4/8 (bound_ctrl: invalid->0), then row_bcast15 (rows 1,3),
// row_bcast31 (rows 2,3). Lane 63 ends with the full 64-lane sum.
__device__ __forceinline__ float wave_sum_dpp(float x) {
    int v;
    v = __builtin_amdgcn_update_dpp(0, __float_as_int(x), 0x111, 0xf, 0xf, true);
    x += __int_as_float(v);
    v = __builtin_amdgcn_update_dpp(0, __float_as_int(x), 0x112, 0xf, 0xf, true);
    x += __int_as_float(v);
    v = __builtin_amdgcn_update_dpp(0, __float_as_int(x), 0x114, 0xf, 0xf, true);
    x += __int_as_float(v);
    v = __builtin_amdgcn_update_dpp(0, __float_as_int(x), 0x118, 0xf, 0xf, true);
    x += __int_as_float(v);
    v = __builtin_amdgcn_update_dpp(0, __float_as_int(x), 0x142, 0xa, 0xf, false);
    x += __int_as_float(v);
    v = __builtin_amdgcn_update_dpp(0, __float_as_int(x), 0x143, 0xc, 0xf, false);
    x += __int_as_float(v);
    return x;
}

// Block-wide barrier WITHOUT the vmcnt(0) drain that __syncthreads emits.
// Only LDS ops (sP/sInvD) need visibility across the barrier; in-flight
// global prefetch loads (read-only, into private VGPRs) legally stay
// outstanding, overlapping part k+1's HBM reads with part k's compute.
__device__ __forceinline__ void sync_lds() {
    asm volatile("s_waitcnt lgkmcnt(0)" ::: "memory");
    __builtin_amdgcn_s_barrier();
    asm volatile("" ::: "memory");
}

constexpr int   kB      = 256;
constexpr int   kC      = 1024;
constexpr int   kG      = 13;
constexpr int   kP      = kG * kG;                // 169
constexpr int   kRP     = 13;                     // positions per part = one row
constexpr float kEps    = 1e-6f;
constexpr float kZ      = 17.079468445347132f;    // 2*pi*e
constexpr float kLog2e  = 1.4426950408889634f;
constexpr float kInv169 = 1.0f / 169.0f;
constexpr float kScale  = 1.0f / (256.0f * 1024.0f);

// One pipelined row step. PART (= grid row h) is compile-time; LAST part
// skips the prefetch. cur holds raw x for row PART; nxt receives the
// prefetch of row PART+1. Position accumulation order is ascending and
// op-for-op identical to the verified R2/R3/R4 kernels -> absmax stays 0.
template<int PART, bool LAST>
__device__ __forceinline__ void do_row(
    const float* __restrict__ xb, int tid, int lane, int wid,
    float (&cur)[kRP], float (&nxt)[kRP],
    float& S0, float& S1x, float& S1y, float& S2x, float& S2y,
    float* __restrict__ sP, float* __restrict__ sInvD)
{
    constexpr int START = PART * kRP;

    // 1) prefetch next row (completion awaited only at next part's exp)
    if (!LAST) {
        const float* __restrict__ xn = xb + (size_t)(START + kRP) * kC + tid;
        #pragma unroll
        for (int i = 0; i < kRP; ++i)
            nxt[i] = xn[(size_t)i * kC];
    }

    // 2) exp (waits only on cur's loads, issued one part earlier)
    #pragma unroll
    for (int i = 0; i < kRP; ++i)
        cur[i] = fast_exp2(cur[i] * kLog2e);

    // 3) per-position wave partial sums on the VALU pipe
    #pragma unroll
    for (int i = 0; i < kRP; ++i) {
        const float s = wave_sum_dpp(cur[i]);
        if (lane == 63) sP[i * 16 + wid] = s;
    }
    sync_lds();

    // 4) 16-way cross-wave tree -> per-position inverse denominator
    if (tid < kRP) {
        float d = 0.f;
        #pragma unroll
        for (int w = 0; w < 16; ++w)
            d += sP[tid * 16 + w];
        sInvD[tid] = 1.0f / (d + 1e-30f);
    }
    sync_lds();

    // 5) stats: h = PART constant, w = i. Same fmaf sequence/values as the
    //    verified kernels (fx=(float)(h+1), fy=(float)(w+1)).
    const float fx = (float)(PART + 1);
    #pragma unroll
    for (int i = 0; i < kRP; ++i) {
        const float f  = cur[i] * sInvD[i];
        const float fy = (float)(i + 1);
        S0  += f;
        S1x  = fmaf(fx,      f, S1x);
        S1y  = fmaf(fy,      f, S1y);
        S2x  = fmaf(fx * fx, f, S2x);
        S2y  = fmaf(fy * fy, f, S2y);
    }
    // sP/sInvD reuse across parts is race-free: writes for part k+1 happen
    // only after every wave passed barrier2 of part k (so the tree reader
    // and all sInvD consumers of part k are done).
}

// ---------------------------------------------------------------------------
// Fully fused, software-pipelined kernel: one block per batch b, 1024
// threads (thread = channel). 13 parts of 13 positions (one grid row each),
// double-buffered e-regs (13+13), raw lgkm-only barriers so prefetch global
// loads stay in flight across barriers.
//
// __launch_bounds__(1024) WITHOUT a min-occupancy arg: the grid is exactly
// 256 blocks = 1 block/CU, so there is nothing to co-schedule and the
// (1024,4) form only capped the allocator at 64 VGPRs -> ~242 MB of scratch
// spill traffic (R3/R4 measured: WRITE_SIZE ~236 MB, VGPR_Count=64).
// The implied cap is now 128 VGPRs (16-wave block launchability), which the
// ~60-register body fits spill-free.
// ---------------------------------------------------------------------------
__global__ __launch_bounds__(1024)
void fused_kernel(const float* __restrict__ x, float* __restrict__ out)
{
    __shared__ float sP[kRP * 16];        // per-(position, wave) partials
    __shared__ float sInvD[kRP];
    __shared__ float sred[16];

    const int tid  = threadIdx.x;
    const int lane = tid & 63;
    const int wid  = tid >> 6;
    const int b    = blockIdx.x;

    const float* __restrict__ xb = x + (size_t)b * kP * kC;

    float e0[kRP], e1[kRP];
    float S0 = 0.f, S1x = 0.f, S1y = 0.f, S2x = 0.f, S2y = 0.f;

    // prologue: load row 0
    {
        const float* __restrict__ xc = xb + tid;
        #pragma unroll
        for (int i = 0; i < kRP; ++i)
            e0[i] = xc[(size_t)i * kC];
    }

    do_row< 0, false>(xb, tid, lane, wid, e0, e1, S0, S1x, S1y, S2x, S2y, sP, sInvD);
    do_row< 1, false>(xb, tid, lane, wid, e1, e0, S0, S1x, S1y, S2x, S2y, sP, sInvD);
    do_row< 2, false>(xb, tid, lane, wid, e0, e1, S0, S1x, S1y, S2x, S2y, sP, sInvD);
    do_row< 3, false>(xb, tid, lane, wid, e1, e0, S0, S1x, S1y, S2x, S2y, sP, sInvD);
    do_row< 4, false>(xb, tid, lane, wid, e0, e1, S0, S1x, S1y, S2x, S2y, sP, sInvD);
    do_row< 5, false>(xb, tid, lane, wid, e1, e0, S0, S1x, S1y, S2x, S2y, sP, sInvD);
    do_row< 6, false>(xb, tid, lane, wid, e0, e1, S0, S1x, S1y, S2x, S2y, sP, sInvD);
    do_row< 7, false>(xb, tid, lane, wid, e1, e0, S0, S1x, S1y, S2x, S2y, sP, sInvD);
    do_row< 8, false>(xb, tid, lane, wid, e0, e1, S0, S1x, S1y, S2x, S2y, sP, sInvD);
    do_row< 9, false>(xb, tid, lane, wid, e1, e0, S0, S1x, S1y, S2x, S2y, sP, sInvD);
    do_row<10, false>(xb, tid, lane, wid, e0, e1, S0, S1x, S1y, S2x, S2y, sP, sInvD);
    do_row<11, false>(xb, tid, lane, wid, e1, e0, S0, S1x, S1y, S2x, S2y, sP, sInvD);
    do_row<12, true >(xb, tid, lane, wid, e0, e1, S0, S1x, S1y, S2x, S2y, sP, sInvD);

    // det epilogue per (b, c) and block-wide mean contribution
    const float s   = S0 + kEps;
    const float is  = 1.0f / s;
    const float mx  = S1x * is;
    const float my  = S1y * is;
    const float nx  = S2x - mx * (2.0f * S1x - mx * S0);
    const float ny  = S2y - my * (2.0f * S1y - my * S0);
    const float t   = (nx + ny) * is * kInv169;
    float det = t * t * kZ;

    #pragma unroll
    for (int m = 1; m < 64; m <<= 1)
        det += __shfl_xor(det, m);

    if (lane == 0) sred[wid] = det;
    __syncthreads();
    if (wid == 0) {
        float v = (lane < 16) ? sred[lane] : 0.0f;
        #pragma unroll
        for (int m = 1; m < 16; m <<= 1)
            v += __shfl_xor(v, m);
        if (lane == 0) atomicAdd(out, v * kScale);
    }
}

extern "C" void kernel_launch(void* const* d_in, const int* in_sizes, int n_in,
                              void* d_out, int out_size, void* d_ws, size_t ws_size,
                              hipStream_t stream)
{
    const float* x   = (const float*)d_in[0];
    float*       out = (float*)d_out;

    // out is tiny (scalar compare); R1->R2 delta proved this memset is ~free.
    hipMemsetAsync(out, 0, sizeof(float) * (size_t)out_size, stream);
    fused_kernel<<<dim3(kB), dim3(1024), 0, stream>>>(x, out);
}